// Round 8
// baseline (105.725 us; speedup 1.0000x reference)
//
#include <hip/hip_runtime.h>
#include <hip/hip_bf16.h>

#define BATCH 8
#define NN 2048
#define FIN 128
#define FOUT 64
#define ROWS_TOTAL (BATCH * NN)           // 16384
#define K1_BLOCKS 512                     // k1 part: 512 blocks x 32 rows
#define K0_BLOCKS 2048                    // mask part: 8192 waves
#define K0_WAVES (K0_BLOCKS * 4)
#define MASK_WORDS (ROWS_TOTAL * (NN / 64))   // 524288 uint64

typedef __attribute__((ext_vector_type(8))) short bf16x8;
typedef __attribute__((ext_vector_type(4))) float f32x4;
typedef __attribute__((ext_vector_type(8))) short short8;

__device__ inline short f2bf(float x) {
    __hip_bfloat16 b = __float2bfloat16(x);   // RNE
    short s;
    __builtin_memcpy(&s, &b, 2);
    return s;
}

// ---------------------------------------------------------------------------
// K01: fused projection (blocks [0,512)) + adj->bitmask compression (rest).
// k1 body is byte-identical to the validated round-1..7 k1.
// k0 body: wave reads 64 consecutive adj floats, ballot(v==0) -> uint64 mask.
// ---------------------------------------------------------------------------
__global__ __launch_bounds__(256) void k01(
        const float* __restrict__ h, const float* __restrict__ W,
        const float* __restrict__ a, const float* __restrict__ adj,
        short* __restrict__ whT, float* __restrict__ wh1, float* __restrict__ wh2,
        unsigned long long* __restrict__ maskg) {
    const int tid  = threadIdx.x;
    const int lane = tid & 63;
    const int wid  = tid >> 6;

    if (blockIdx.x < K1_BLOCKS) {
        // ---------------- k1: wh = h @ W, whT bf16, wh1/wh2 ----------------
        const int gw   = blockIdx.x * 4 + wid;
        const int row0 = gw * 8;
        const int b    = row0 >> 11;
        const int rloc = row0 & (NN - 1);

        float acc[8] = {0.f,0.f,0.f,0.f,0.f,0.f,0.f,0.f};
        const float* hrow = h + (size_t)row0 * FIN;

        #pragma unroll 2
        for (int kc = 0; kc < FIN / 4; ++kc) {
            float wv0 = W[(4*kc + 0) * FOUT + lane];
            float wv1 = W[(4*kc + 1) * FOUT + lane];
            float wv2 = W[(4*kc + 2) * FOUT + lane];
            float wv3 = W[(4*kc + 3) * FOUT + lane];
            #pragma unroll
            for (int r = 0; r < 8; ++r) {
                float4 h4 = *(const float4*)(hrow + r * FIN + 4*kc);
                acc[r] = fmaf(h4.x, wv0, acc[r]);
                acc[r] = fmaf(h4.y, wv1, acc[r]);
                acc[r] = fmaf(h4.z, wv2, acc[r]);
                acc[r] = fmaf(h4.w, wv3, acc[r]);
            }
        }

        short8 st;
        #pragma unroll
        for (int r = 0; r < 8; ++r) st[r] = f2bf(acc[r]);
        *(short8*)(whT + ((size_t)b * FOUT + lane) * NN + rloc) = st;

        const float a1 = a[lane];
        const float a2 = a[FOUT + lane];
        #pragma unroll
        for (int r = 0; r < 8; ++r) {
            const int row = row0 + r;
            float v1 = acc[r] * a1;
            float v2 = acc[r] * a2;
            #pragma unroll
            for (int m = 32; m >= 1; m >>= 1) {
                v1 += __shfl_xor(v1, m, 64);
                v2 += __shfl_xor(v2, m, 64);
            }
            if (lane == 0) { wh1[row] = v1; wh2[row] = v2; }
        }
    } else {
        // ---------------- k0: adj -> bitmask (dense stream) ----------------
        const int gw = (blockIdx.x - K1_BLOCKS) * 4 + wid;   // 0..8191
        #pragma unroll 4
        for (int it = 0; it < MASK_WORDS / K0_WAVES; ++it) {   // 64 iters
            const size_t wd = (size_t)it * K0_WAVES + gw;
            float v = adj[wd * 64 + lane];
            unsigned long long m = __ballot(v == 0.0f);   // bit lane <-> j offset
            if (lane == 0) maskg[wd] = m;
        }
    }
}

// ---------------------------------------------------------------------------
// K2 v5: mask-driven fused softmax+PV via MFMA, layout-self-calibrated.
// No adj stream, no staging, no in-loop barriers. 16 rows x 8 waves; wave w
// owns j = cn*256 + w*32 + [0,32) per phase cn. Mask: 4 KB LDS preload.
// ---------------------------------------------------------------------------
__global__ __launch_bounds__(512) void k2_attn(
        const unsigned long long* __restrict__ maskg, const short* __restrict__ whT,
        const float* __restrict__ wh1, const float* __restrict__ wh2,
        float* __restrict__ out) {
    __shared__ unsigned long long lds_mask64[512];   // 4 KB: [16 rows][32 words]
    __shared__ float lds_acc[8][16][FOUT];           // 32 KB
    __shared__ float lds_l[8][16];

    const int tid  = threadIdx.x;
    const int lane = tid & 63;
    const int w    = tid >> 6;               // 0..7
    const int row0 = blockIdx.x * 16;
    const int b    = row0 >> 11;
    const int iloc = lane & 15;
    const int kg   = lane >> 4;              // 0..3

    const float* wh2b = wh2 + b * NN;
    const short* whTb = whT + (size_t)b * FOUT * NN;
    const float  wh1v = wh1[row0 + iloc];

    // mask preload: rows row0..row0+15 = 512 uint64, one per thread
    lds_mask64[tid] = maskg[(size_t)row0 * 32 + tid];

    // --- layout self-calibration (proven round 3) ---
    bf16x8 onesf, idxf;
    #pragma unroll
    for (int e = 0; e < 8; ++e) { onesf[e] = (short)0x3F80; idxf[e] = f2bf((float)iloc); }
    f32x4 rowM = {}, colM = {};
    rowM = __builtin_amdgcn_mfma_f32_16x16x32_bf16(idxf, onesf, rowM, 0, 0, 0);
    colM = __builtin_amdgcn_mfma_f32_16x16x32_bf16(onesf, idxf, colM, 0, 0, 0);
    int rmap[4], cmap[4];
    #pragma unroll
    for (int reg = 0; reg < 4; ++reg) {
        int r = (int)(rowM[reg] * 0.03125f + 0.5f);
        int c = (int)(colM[reg] * 0.03125f + 0.5f);
        rmap[reg] = min(max(r, 0), 15);
        cmap[reg] = min(max(c, 0), 15);
    }

    __syncthreads();   // mask ready
    const unsigned char* mb8 = (const unsigned char*)lds_mask64;

    f32x4 acc[4] = {};
    f32x4 accl = {};

    #pragma unroll 2
    for (int cn = 0; cn < 8; ++cn) {
        const int j0 = cn * 256 + w * 32 + kg * 8;

        // mask byte: bits e=0..7 <-> j0+e  (flat byte = row*256 + j/8)
        const unsigned int mb = mb8[iloc * 256 + cn * 32 + w * 4 + kg];

        float4 w0 = *(const float4*)(wh2b + j0);
        float4 w1 = *(const float4*)(wh2b + j0 + 4);

        bf16x8 bf[4];
        #pragma unroll
        for (int ft = 0; ft < 4; ++ft)
            bf[ft] = *(const bf16x8*)(whTb + (size_t)(ft * 16 + iloc) * NN + j0);

        float pv[8];
        {
            float e, pe;
            e = wh1v + w0.x; pe = __expf(fmaxf(e, 0.2f*e)); pv[0] = (mb & 1u)   ? pe : 0.f;
            e = wh1v + w0.y; pe = __expf(fmaxf(e, 0.2f*e)); pv[1] = (mb & 2u)   ? pe : 0.f;
            e = wh1v + w0.z; pe = __expf(fmaxf(e, 0.2f*e)); pv[2] = (mb & 4u)   ? pe : 0.f;
            e = wh1v + w0.w; pe = __expf(fmaxf(e, 0.2f*e)); pv[3] = (mb & 8u)   ? pe : 0.f;
            e = wh1v + w1.x; pe = __expf(fmaxf(e, 0.2f*e)); pv[4] = (mb & 16u)  ? pe : 0.f;
            e = wh1v + w1.y; pe = __expf(fmaxf(e, 0.2f*e)); pv[5] = (mb & 32u)  ? pe : 0.f;
            e = wh1v + w1.z; pe = __expf(fmaxf(e, 0.2f*e)); pv[6] = (mb & 64u)  ? pe : 0.f;
            e = wh1v + w1.w; pe = __expf(fmaxf(e, 0.2f*e)); pv[7] = (mb & 128u) ? pe : 0.f;
        }
        bf16x8 af;
        #pragma unroll
        for (int e = 0; e < 8; ++e) af[e] = f2bf(pv[e]);

        accl = __builtin_amdgcn_mfma_f32_16x16x32_bf16(af, onesf, accl, 0, 0, 0);
        #pragma unroll
        for (int ft = 0; ft < 4; ++ft)
            acc[ft] = __builtin_amdgcn_mfma_f32_16x16x32_bf16(af, bf[ft], acc[ft], 0, 0, 0);
    }

    // stash partials using the MEASURED layout maps
    #pragma unroll
    for (int ft = 0; ft < 4; ++ft)
        #pragma unroll
        for (int reg = 0; reg < 4; ++reg)
            lds_acc[w][rmap[reg]][ft * 16 + cmap[reg]] = acc[ft][reg];
    #pragma unroll
    for (int reg = 0; reg < 4; ++reg)
        if (cmap[reg] == 0) lds_l[w][rmap[reg]] = accl[reg];
    __syncthreads();

    // combine across 8 waves + normalize + elu; thread -> (f, 2 rows)
    const int f  = tid & 63;
    const int rh = tid >> 6;                 // 0..7
    #pragma unroll
    for (int rr = 0; rr < 2; ++rr) {
        const int r = rh * 2 + rr;
        float s = 0.f, l = 0.f;
        #pragma unroll
        for (int ww = 0; ww < 8; ++ww) {
            s += lds_acc[ww][r][f];
            l += lds_l[ww][r];
        }
        float v = s / l;
        out[(size_t)(row0 + r) * FOUT + f] = (v > 0.f) ? v : (__expf(v) - 1.f);
    }
}

// ---------------------------------------------------------------------------
extern "C" void kernel_launch(void* const* d_in, const int* in_sizes, int n_in,
                              void* d_out, int out_size, void* d_ws, size_t ws_size,
                              hipStream_t stream) {
    const float* h   = (const float*)d_in[0];   // [8,2048,128]
    const float* adj = (const float*)d_in[1];   // [8,2048,2048]
    const float* W   = (const float*)d_in[2];   // [128,64]
    const float* a   = (const float*)d_in[3];   // [128,1]
    float* out = (float*)d_out;                 // [8,2048,64]

    short* whT = (short*)d_ws;                              // 2 MB bf16 [8][64][2048]
    float* wh1 = (float*)(whT + (size_t)BATCH * FOUT * NN); // 64 KB
    float* wh2 = wh1 + ROWS_TOTAL;                          // 64 KB
    unsigned long long* maskg = (unsigned long long*)(wh2 + ROWS_TOTAL);  // 4 MB

    k01<<<K1_BLOCKS + K0_BLOCKS, 256, 0, stream>>>(h, W, a, adj, whT, wh1, wh2, maskg);
    k2_attn<<<ROWS_TOTAL / 16, 512, 0, stream>>>(maskg, whT, wh1, wh2, out);
}

// Round 9
// 74.049 us; speedup vs baseline: 1.4278x; 1.4278x over previous
//
#include <hip/hip_runtime.h>
#include <hip/hip_bf16.h>

#define BATCH 8
#define NN 2048
#define FIN 128
#define FOUT 64
#define ROWS_TOTAL (BATCH * NN)           // 16384
#define K1_BLOCKS 512                     // k1 part: 512 blocks x 32 rows
#define K0_BLOCKS 2048                    // mask part
#define K0_THREADS (K0_BLOCKS * 256)      // 524288
#define MASK_BYTES (ROWS_TOTAL * (NN / 8))    // 4 MB = 4.19M bytes

typedef __attribute__((ext_vector_type(8))) short bf16x8;
typedef __attribute__((ext_vector_type(4))) float f32x4;
typedef __attribute__((ext_vector_type(8))) short short8;

__device__ inline short f2bf(float x) {
    __hip_bfloat16 b = __float2bfloat16(x);   // RNE
    short s;
    __builtin_memcpy(&s, &b, 2);
    return s;
}

// ---------------------------------------------------------------------------
// K01: fused projection (blocks [0,512)) + adj->bitmask compression (rest).
// k1 body byte-identical to validated rounds 1..8.
// k0 body: m13-shape streaming — 16 independent float4 loads per thread
// (256 B in flight), then 8 byte-packs + 8 byte stores. No cross-lane ops.
// Byte g covers j-octet g: bit e = (adj[8g+e] == 0).
// ---------------------------------------------------------------------------
__global__ __launch_bounds__(256) void k01(
        const float* __restrict__ h, const float* __restrict__ W,
        const float* __restrict__ a, const float* __restrict__ adj,
        short* __restrict__ whT, float* __restrict__ wh1, float* __restrict__ wh2,
        unsigned char* __restrict__ maskb) {
    const int tid  = threadIdx.x;
    const int lane = tid & 63;
    const int wid  = tid >> 6;

    if (blockIdx.x < K1_BLOCKS) {
        // ---------------- k1: wh = h @ W, whT bf16, wh1/wh2 ----------------
        const int gw   = blockIdx.x * 4 + wid;
        const int row0 = gw * 8;
        const int b    = row0 >> 11;
        const int rloc = row0 & (NN - 1);

        float acc[8] = {0.f,0.f,0.f,0.f,0.f,0.f,0.f,0.f};
        const float* hrow = h + (size_t)row0 * FIN;

        #pragma unroll 2
        for (int kc = 0; kc < FIN / 4; ++kc) {
            float wv0 = W[(4*kc + 0) * FOUT + lane];
            float wv1 = W[(4*kc + 1) * FOUT + lane];
            float wv2 = W[(4*kc + 2) * FOUT + lane];
            float wv3 = W[(4*kc + 3) * FOUT + lane];
            #pragma unroll
            for (int r = 0; r < 8; ++r) {
                float4 h4 = *(const float4*)(hrow + r * FIN + 4*kc);
                acc[r] = fmaf(h4.x, wv0, acc[r]);
                acc[r] = fmaf(h4.y, wv1, acc[r]);
                acc[r] = fmaf(h4.z, wv2, acc[r]);
                acc[r] = fmaf(h4.w, wv3, acc[r]);
            }
        }

        short8 st;
        #pragma unroll
        for (int r = 0; r < 8; ++r) st[r] = f2bf(acc[r]);
        *(short8*)(whT + ((size_t)b * FOUT + lane) * NN + rloc) = st;

        const float a1 = a[lane];
        const float a2 = a[FOUT + lane];
        #pragma unroll
        for (int r = 0; r < 8; ++r) {
            const int row = row0 + r;
            float v1 = acc[r] * a1;
            float v2 = acc[r] * a2;
            #pragma unroll
            for (int m = 32; m >= 1; m >>= 1) {
                v1 += __shfl_xor(v1, m, 64);
                v2 += __shfl_xor(v2, m, 64);
            }
            if (lane == 0) { wh1[row] = v1; wh2[row] = v2; }
        }
    } else {
        // ---------------- k0: adj -> bitmask, deep-ILP stream ----------------
        const int tgl = (blockIdx.x - K1_BLOCKS) * 256 + tid;   // 0..524287
        const float4* adj4 = (const float4*)adj;

        // phase 1: issue all 16 loads (independent -> all in flight)
        float4 va[8], vb[8];
        #pragma unroll
        for (int it = 0; it < 8; ++it) {
            const size_t g = (size_t)it * K0_THREADS + tgl;     // byte/octet index
            va[it] = adj4[2 * g];
            vb[it] = adj4[2 * g + 1];
        }
        // phase 2: pack + store bytes
        #pragma unroll
        for (int it = 0; it < 8; ++it) {
            const size_t g = (size_t)it * K0_THREADS + tgl;
            unsigned int by =
                (va[it].x == 0.f ? 1u   : 0u) | (va[it].y == 0.f ? 2u   : 0u) |
                (va[it].z == 0.f ? 4u   : 0u) | (va[it].w == 0.f ? 8u   : 0u) |
                (vb[it].x == 0.f ? 16u  : 0u) | (vb[it].y == 0.f ? 32u  : 0u) |
                (vb[it].z == 0.f ? 64u  : 0u) | (vb[it].w == 0.f ? 128u : 0u);
            maskb[g] = (unsigned char)by;
        }
    }
}

// ---------------------------------------------------------------------------
// K2 v5 (unchanged — validated round 8): mask-driven fused softmax+PV via
// MFMA, layout-self-calibrated. No adj stream, no in-loop barriers.
// 16 rows x 8 waves; wave w owns j = cn*256 + w*32 + [0,32) per phase.
// ---------------------------------------------------------------------------
__global__ __launch_bounds__(512) void k2_attn(
        const unsigned long long* __restrict__ maskg, const short* __restrict__ whT,
        const float* __restrict__ wh1, const float* __restrict__ wh2,
        float* __restrict__ out) {
    __shared__ unsigned long long lds_mask64[512];   // 4 KB: [16 rows][32 words]
    __shared__ float lds_acc[8][16][FOUT];           // 32 KB
    __shared__ float lds_l[8][16];

    const int tid  = threadIdx.x;
    const int lane = tid & 63;
    const int w    = tid >> 6;               // 0..7
    const int row0 = blockIdx.x * 16;
    const int b    = row0 >> 11;
    const int iloc = lane & 15;
    const int kg   = lane >> 4;              // 0..3

    const float* wh2b = wh2 + b * NN;
    const short* whTb = whT + (size_t)b * FOUT * NN;
    const float  wh1v = wh1[row0 + iloc];

    // mask preload: rows row0..row0+15 = 512 uint64, one per thread
    lds_mask64[tid] = maskg[(size_t)row0 * 32 + tid];

    // --- layout self-calibration (proven round 3) ---
    bf16x8 onesf, idxf;
    #pragma unroll
    for (int e = 0; e < 8; ++e) { onesf[e] = (short)0x3F80; idxf[e] = f2bf((float)iloc); }
    f32x4 rowM = {}, colM = {};
    rowM = __builtin_amdgcn_mfma_f32_16x16x32_bf16(idxf, onesf, rowM, 0, 0, 0);
    colM = __builtin_amdgcn_mfma_f32_16x16x32_bf16(onesf, idxf, colM, 0, 0, 0);
    int rmap[4], cmap[4];
    #pragma unroll
    for (int reg = 0; reg < 4; ++reg) {
        int r = (int)(rowM[reg] * 0.03125f + 0.5f);
        int c = (int)(colM[reg] * 0.03125f + 0.5f);
        rmap[reg] = min(max(r, 0), 15);
        cmap[reg] = min(max(c, 0), 15);
    }

    __syncthreads();   // mask ready
    const unsigned char* mb8 = (const unsigned char*)lds_mask64;

    f32x4 acc[4] = {};
    f32x4 accl = {};

    #pragma unroll 2
    for (int cn = 0; cn < 8; ++cn) {
        const int j0 = cn * 256 + w * 32 + kg * 8;

        // mask byte: bits e=0..7 <-> j0+e  (flat byte = row*256 + j/8)
        const unsigned int mb = mb8[iloc * 256 + cn * 32 + w * 4 + kg];

        float4 w0 = *(const float4*)(wh2b + j0);
        float4 w1 = *(const float4*)(wh2b + j0 + 4);

        bf16x8 bf[4];
        #pragma unroll
        for (int ft = 0; ft < 4; ++ft)
            bf[ft] = *(const bf16x8*)(whTb + (size_t)(ft * 16 + iloc) * NN + j0);

        float pv[8];
        {
            float e, pe;
            e = wh1v + w0.x; pe = __expf(fmaxf(e, 0.2f*e)); pv[0] = (mb & 1u)   ? pe : 0.f;
            e = wh1v + w0.y; pe = __expf(fmaxf(e, 0.2f*e)); pv[1] = (mb & 2u)   ? pe : 0.f;
            e = wh1v + w0.z; pe = __expf(fmaxf(e, 0.2f*e)); pv[2] = (mb & 4u)   ? pe : 0.f;
            e = wh1v + w0.w; pe = __expf(fmaxf(e, 0.2f*e)); pv[3] = (mb & 8u)   ? pe : 0.f;
            e = wh1v + w1.x; pe = __expf(fmaxf(e, 0.2f*e)); pv[4] = (mb & 16u)  ? pe : 0.f;
            e = wh1v + w1.y; pe = __expf(fmaxf(e, 0.2f*e)); pv[5] = (mb & 32u)  ? pe : 0.f;
            e = wh1v + w1.z; pe = __expf(fmaxf(e, 0.2f*e)); pv[6] = (mb & 64u)  ? pe : 0.f;
            e = wh1v + w1.w; pe = __expf(fmaxf(e, 0.2f*e)); pv[7] = (mb & 128u) ? pe : 0.f;
        }
        bf16x8 af;
        #pragma unroll
        for (int e = 0; e < 8; ++e) af[e] = f2bf(pv[e]);

        accl = __builtin_amdgcn_mfma_f32_16x16x32_bf16(af, onesf, accl, 0, 0, 0);
        #pragma unroll
        for (int ft = 0; ft < 4; ++ft)
            acc[ft] = __builtin_amdgcn_mfma_f32_16x16x32_bf16(af, bf[ft], acc[ft], 0, 0, 0);
    }

    // stash partials using the MEASURED layout maps
    #pragma unroll
    for (int ft = 0; ft < 4; ++ft)
        #pragma unroll
        for (int reg = 0; reg < 4; ++reg)
            lds_acc[w][rmap[reg]][ft * 16 + cmap[reg]] = acc[ft][reg];
    #pragma unroll
    for (int reg = 0; reg < 4; ++reg)
        if (cmap[reg] == 0) lds_l[w][rmap[reg]] = accl[reg];
    __syncthreads();

    // combine across 8 waves + normalize + elu; thread -> (f, 2 rows)
    const int f  = tid & 63;
    const int rh = tid >> 6;                 // 0..7
    #pragma unroll
    for (int rr = 0; rr < 2; ++rr) {
        const int r = rh * 2 + rr;
        float s = 0.f, l = 0.f;
        #pragma unroll
        for (int ww = 0; ww < 8; ++ww) {
            s += lds_acc[ww][r][f];
            l += lds_l[ww][r];
        }
        float v = s / l;
        out[(size_t)(row0 + r) * FOUT + f] = (v > 0.f) ? v : (__expf(v) - 1.f);
    }
}

// ---------------------------------------------------------------------------
extern "C" void kernel_launch(void* const* d_in, const int* in_sizes, int n_in,
                              void* d_out, int out_size, void* d_ws, size_t ws_size,
                              hipStream_t stream) {
    const float* h   = (const float*)d_in[0];   // [8,2048,128]
    const float* adj = (const float*)d_in[1];   // [8,2048,2048]
    const float* W   = (const float*)d_in[2];   // [128,64]
    const float* a   = (const float*)d_in[3];   // [128,1]
    float* out = (float*)d_out;                 // [8,2048,64]

    short* whT = (short*)d_ws;                              // 2 MB bf16 [8][64][2048]
    float* wh1 = (float*)(whT + (size_t)BATCH * FOUT * NN); // 64 KB
    float* wh2 = wh1 + ROWS_TOTAL;                          // 64 KB
    unsigned char* maskb = (unsigned char*)(wh2 + ROWS_TOTAL);  // 4 MB

    k01<<<K1_BLOCKS + K0_BLOCKS, 256, 0, stream>>>(h, W, a, adj, whT, wh1, wh2, maskb);
    k2_attn<<<ROWS_TOTAL / 16, 512, 0, stream>>>((const unsigned long long*)maskb,
                                                 whT, wh1, wh2, out);
}